// Round 8
// baseline (379.351 us; speedup 1.0000x reference)
//
#include <hip/hip_runtime.h>
#include <stdint.h>

typedef _Float16 f16;
typedef _Float16 f16x8 __attribute__((ext_vector_type(8)));
typedef _Float16 f16x4 __attribute__((ext_vector_type(4)));
typedef _Float16 f16x2 __attribute__((ext_vector_type(2)));
typedef float f32x4 __attribute__((ext_vector_type(4)));

__device__ __forceinline__ f32x4 mfma16(f16x8 a, f16x8 b, f32x4 c) {
    return __builtin_amdgcn_mfma_f32_16x16x32_f16(a, b, c, 0, 0, 0);
}

// Async global->LDS, 16B per lane (used by attention only now).
__device__ __forceinline__ void gload16(const f16* g, f16* l) {
    __builtin_amdgcn_global_load_lds(
        (const __attribute__((address_space(1))) uint32_t*)g,
        (__attribute__((address_space(3))) uint32_t*)l, 16, 0, 0);
}

// RN fp32x8 -> f16x8 (same rounding as the original cvt path)
__device__ __forceinline__ f16x8 cvt8(f32x4 a, f32x4 b) {
    f16x8 h;
    h[0] = (f16)a[0]; h[1] = (f16)a[1]; h[2] = (f16)a[2]; h[3] = (f16)a[3];
    h[4] = (f16)b[0]; h[5] = (f16)b[1]; h[6] = (f16)b[2]; h[7] = (f16)b[3];
    return h;
}

// ---------------------------------------------------------------------------
// Fused-convert GEMM v2: C[m][n] = (sum_k D/S[m][k]*S/D[n][k]+bias)*scale,
// K=1024, 128x128 tile, 4 waves 2x2, BK=32, 32 K-iters.
//
// ROUND-8 FIX of r7's exposed-latency failure (qkv 121us, MfmaUtil 17%):
// the HBM-streamed operand ("deep", D) is staged through a 3-set register
// rotation: loads for tile kt+3 issue at iter kt, cvt+ds_write at iter
// kt+2 -> TWO full iterations (~600-900cy) between issue and the
// compiler-inserted vmcnt wait, crossing two sched_barrier(0)s so the
// loads cannot sink. The L2-resident operand ("shallow", S = weights,
// XCD-pinned by the grid swizzle) keeps same-iter staging (L2 ~200cy is
// covered by the 16-MFMA block). LDS = 3 slots x (8KB+8KB) = 48KB.
// Deep operand is fp32 (qkv) or f16 (o_proj: Op) via DEEP16.
//
// LDS layout identical to the 7-round-proven swizzle:
//   LDS[row][c] = src[row][c ^ ((row>>1)&3)]  (row-major 128 x 32 f16)
// write: chunk g=lane&3 stored at sc=g^((r4>>1)&3); read: chunk index
// quad^((l15>>1)&3) retrieves source chunk quad for every lane.
// ---------------------------------------------------------------------------
template <bool DEEP16, bool OUT16>
__device__ __forceinline__ void gemm_fused(
    const void* __restrict__ Dmat, const float* __restrict__ Smat,
    long d0, long s0, bool deepA, const float* __restrict__ bias,
    void* __restrict__ Cout, long ldo, int biasrow, float scale,
    long m0, long n0, f16* As, f16* Bs) {
    int tid = threadIdx.x;
    int lane = tid & 63, w = tid >> 6;
    int wm = w & 1, wn = w >> 1;
    int l15 = lane & 15, quad = lane >> 4;
    int r4 = lane >> 2;             // row within 16-row group
    int g = lane & 3;               // source chunk (8 f16 / 8 f32)
    int sc = g ^ ((r4 >> 1) & 3);   // stored chunk position
    int cs = (quad ^ ((l15 >> 1) & 3)) * 8;  // read chunk offset

    const f16* d16src[2];
    const float* d32src[2];
    const float* ssrc[2];
    int lw[2];
#pragma unroll
    for (int t = 0; t < 2; ++t) {
        long row = t * 64 + w * 16 + r4;
        if constexpr (DEEP16)
            d16src[t] = (const f16*)Dmat + (d0 + row) * 1024 + g * 8;
        else
            d32src[t] = (const float*)Dmat + (d0 + row) * 1024 + g * 8;
        ssrc[t] = Smat + (s0 + row) * 1024 + g * 8;
        lw[t] = t * 2048 + w * 512 + r4 * 32 + sc * 8;
    }
    f16* Dlds = deepA ? As : Bs;
    f16* Slds = deepA ? Bs : As;

    // deep register sets (3-deep rotation; all indices compile-time)
    f32x4 dd[3][2][2];
    f16x8 dh[3][2];
    f32x4 acc[4][4] = {};

#define ISSUE_D(SET, KO)                                                      \
    do {                                                                      \
        _Pragma("unroll") for (int t_ = 0; t_ < 2; ++t_) {                    \
            if constexpr (DEEP16) {                                           \
                dh[SET][t_] = *(const f16x8*)(d16src[t_] + (KO));             \
            } else {                                                          \
                dd[SET][t_][0] = *(const f32x4*)(d32src[t_] + (KO));          \
                dd[SET][t_][1] = *(const f32x4*)(d32src[t_] + (KO) + 4);      \
            }                                                                 \
        }                                                                     \
    } while (0)

#define COMMIT_D(SET, SLOT)                                                   \
    do {                                                                      \
        _Pragma("unroll") for (int t_ = 0; t_ < 2; ++t_) {                    \
            if constexpr (DEEP16)                                             \
                *(f16x8*)&Dlds[(SLOT) * 4096 + lw[t_]] = dh[SET][t_];         \
            else                                                              \
                *(f16x8*)&Dlds[(SLOT) * 4096 + lw[t_]] =                      \
                    cvt8(dd[SET][t_][0], dd[SET][t_][1]);                     \
        }                                                                     \
    } while (0)

#define STAGE_S(KO)                                                           \
    do {                                                                      \
        _Pragma("unroll") for (int t_ = 0; t_ < 2; ++t_) {                    \
            ls[t_][0] = *(const f32x4*)(ssrc[t_] + (KO));                     \
            ls[t_][1] = *(const f32x4*)(ssrc[t_] + (KO) + 4);                 \
        }                                                                     \
    } while (0)

#define COMMIT_S(SLOT)                                                        \
    do {                                                                      \
        _Pragma("unroll") for (int t_ = 0; t_ < 2; ++t_)                      \
            *(f16x8*)&Slds[(SLOT) * 4096 + lw[t_]] =                          \
                cvt8(ls[t_][0], ls[t_][1]);                                   \
    } while (0)

#define COMPUTE(SLOT)                                                         \
    do {                                                                      \
        const f16* as_ = As + (SLOT) * 4096;                                  \
        const f16* bs_ = Bs + (SLOT) * 4096;                                  \
        f16x8 af[4], bf[4];                                                   \
        _Pragma("unroll") for (int t_ = 0; t_ < 4; ++t_) {                    \
            af[t_] = *(const f16x8*)&as_[(wm * 64 + t_ * 16 + l15) * 32 + cs];\
            bf[t_] = *(const f16x8*)&bs_[(wn * 64 + t_ * 16 + l15) * 32 + cs];\
        }                                                                     \
        __builtin_amdgcn_s_setprio(1);                                        \
        _Pragma("unroll") for (int i_ = 0; i_ < 4; ++i_)                      \
            _Pragma("unroll") for (int j_ = 0; j_ < 4; ++j_)                  \
                acc[i_][j_] = mfma16(af[i_], bf[j_], acc[i_][j_]);            \
        __builtin_amdgcn_s_setprio(0);                                        \
    } while (0)

#define SYNC()                                                                \
    do {                                                                      \
        asm volatile("s_waitcnt lgkmcnt(0)" ::: "memory");                    \
        __builtin_amdgcn_s_barrier();                                         \
        __builtin_amdgcn_sched_barrier(0);                                    \
    } while (0)

// iter KT: issue deep set SI <- tile KT+3; stage shallow tile KT+1;
// compute LDS slot SLC (= KT%3); commit deep set SC (tile KT+1) + shallow
// into slot SLW (= (KT+1)%3); fence.
#define GBODY(KT, SI, SC, SLC, SLW)                                           \
    do {                                                                      \
        f32x4 ls[2][2];                                                       \
        if ((KT) <= 28) ISSUE_D(SI, (long)((KT) + 3) * 32);                   \
        if ((KT) <= 30) STAGE_S((long)((KT) + 1) * 32);                       \
        COMPUTE(SLC);                                                         \
        if ((KT) <= 30) {                                                     \
            COMMIT_D(SC, SLW);                                                \
            COMMIT_S(SLW);                                                    \
            SYNC();                                                           \
        }                                                                     \
    } while (0)

    // prologue: tile0 staged+committed; tiles 1,2 in flight (sets 1,2)
    ISSUE_D(0, 0);
    {
        f32x4 ls[2][2];
        STAGE_S(0);
        COMMIT_D(0, 0);
        COMMIT_S(0);
    }
    ISSUE_D(1, 32);
    ISSUE_D(2, 64);
    SYNC();

    for (int kt = 0; kt < 30; kt += 3) {
        GBODY(kt, 0, 1, 0, 1);
        GBODY(kt + 1, 1, 2, 1, 2);
        GBODY(kt + 2, 2, 0, 2, 0);
    }
    GBODY(30, 0, 1, 0, 1);  // no issue (guard)
    GBODY(31, 1, 2, 1, 2);  // compute-only (guards)

#undef ISSUE_D
#undef COMMIT_D
#undef STAGE_S
#undef COMMIT_S
#undef COMPUTE
#undef SYNC
#undef GBODY

    // C/D layout: col = lane&15, row = quad*4 + reg
#pragma unroll
    for (int i = 0; i < 4; ++i) {
        int mrow = wm * 64 + i * 16 + quad * 4;
#pragma unroll
        for (int j = 0; j < 4; ++j) {
            int ncol = wn * 64 + j * 16 + l15;
            long gn = n0 + ncol;
#pragma unroll
            for (int r = 0; r < 4; ++r) {
                long gm = m0 + mrow + r;
                float v = (acc[i][j][r] + (biasrow ? bias[gm] : bias[gn])) * scale;
                if constexpr (OUT16)
                    ((f16*)Cout)[gm * ldo + gn] = (f16)v;
                else
                    ((float*)Cout)[gm * ldo + gn] = v;
            }
        }
    }
}

// Merged Q/K/V projection reading RAW fp32 inputs. Grid (64,8,3) remapped
// XCD-aware: lin = bx + 64*by + 512*bz round-robins XCDs (lin&7); we
// assign y' = xcd so each 512KB weight panel is owned by ONE XCD (L2-
// pinned; r7 FETCH showed ~40MB of cross-XCD weight refetch). z' = s>>6,
// x' = s&63 cover all (x,y,z) bijectively.
// z=0: Qp = (q@Wq^T+bq)*log2e/32 ; z=1: Kp ; z=2: Vt = (Wv x v^T).
// Deep operand = HBM stream (q/k for z<=1, v for z=2); shallow = weight.
__global__ __launch_bounds__(256, 2) void qkv_proj(
    const float* __restrict__ q, const float* __restrict__ k,
    const float* __restrict__ v, const float* __restrict__ Wq,
    const float* __restrict__ Wk, const float* __restrict__ Wv,
    const float* __restrict__ bq, const float* __restrict__ bk,
    const float* __restrict__ bv, f16* __restrict__ Qp, f16* __restrict__ Kp,
    f16* __restrict__ Vt) {
    __shared__ __align__(16) f16 As[3 * 4096];
    __shared__ __align__(16) f16 Bs[3 * 4096];
    int lin = blockIdx.x + (blockIdx.y << 6) + (blockIdx.z << 9);
    int xcd = lin & 7;
    int s = lin >> 3;
    int z = s >> 6;   // 0..2
    int xi = s & 63;  // 0..63
    int yi = xcd;     // 0..7  (weight panel -> XCD-pinned)

    const float* D;
    const float* S;
    const float* bias;
    f16* C;
    long ldo;
    int biasrow;
    float scale;
    long m0, n0, d0, s0;
    bool deepA;
    if (z == 2) {
        m0 = (long)yi * 128;  // embed rows (Wv)
        n0 = (long)xi * 128;  // token cols
        D = v; d0 = n0; S = Wv; s0 = m0; deepA = false;
        bias = bv; C = Vt; ldo = 8192; biasrow = 1; scale = 1.0f;
    } else {
        m0 = (long)xi * 128;  // token rows
        n0 = (long)yi * 128;  // embed cols (weight panel)
        D = (z == 0) ? q : k; d0 = m0;
        S = (z == 0) ? Wq : Wk; s0 = n0;
        deepA = true;
        bias = (z == 0) ? bq : bk;
        C = (z == 0) ? Qp : Kp;
        ldo = 1024; biasrow = 0;
        scale = (z == 0) ? 0.0450842200277786f : 1.0f;  // log2(e)/32
    }
    gemm_fused<false, true>(D, S, d0, s0, deepA, bias, C, ldo, biasrow,
                            scale, m0, n0, As, Bs);
}

// Output projection: out = Op@Wo^T + bo (fp32 out). Deep = Op (f16, HBM);
// shallow = Wo fp32 (XCD-pinned panel via n0 = xcd*128).
__global__ __launch_bounds__(256, 2) void o_proj(const f16* __restrict__ Op,
                                                 const float* __restrict__ Wo,
                                                 const float* __restrict__ bo,
                                                 float* __restrict__ out) {
    __shared__ __align__(16) f16 As[3 * 4096];
    __shared__ __align__(16) f16 Bs[3 * 4096];
    int lin = blockIdx.x + (blockIdx.y << 6);
    int xcd = lin & 7;
    int s = lin >> 3;           // 0..63 token panel
    long m0 = (long)s * 128;
    long n0 = (long)xcd * 128;  // weight panel -> XCD-pinned
    gemm_fused<true, false>(Op, Wo, m0, n0, true, bo, out, 1024, 0, 1.0f,
                            m0, n0, As, Bs);
}

// ---------------------------------------------------------------------------
// Attention v7 (unchanged -- proven 84.6us, counter-verified r5): 512 blocks,
// 256-row q-pair, K/V tiles shared by both q-tiles, K/V TRIPLE-buffered
// (80KB LDS), prefetch tile kt+2, s_waitcnt vmcnt(4) + raw s_barrier per kt
// (T4 counted: tile kt+1 retired, kt+2 stays in flight). vmcnt(0) only at
// kt=30. P ds_writes wave-private. K/V LDS-staged (r4: per-wave L2 reads
// quadrupled traffic, -50%).
// ---------------------------------------------------------------------------
__global__ __launch_bounds__(256, 2) void attn256(const f16* __restrict__ Qp,
                                                  const f16* __restrict__ Kp,
                                                  const f16* __restrict__ Vt,
                                                  f16* __restrict__ Op) {
    __shared__ __align__(16) f16 Ps0[128 * 64];
    __shared__ __align__(16) f16 Ps1[128 * 64];
    __shared__ __align__(16) f16 Ks[3][64 * 64];
    __shared__ __align__(16) f16 Vs[3][64 * 64];

    int tid = threadIdx.x;
    int lane = tid & 63, w = tid >> 6;
    int l15 = lane & 15, quad = lane >> 4;
    int b = blockIdx.x;
    int xcd = b & 7, slot = b >> 3;        // 64 slots per XCD
    int nh = xcd * 8 + (slot >> 3);        // 8 (n,h) per XCD
    int qp = slot & 7;                     // 8 q-pairs per (n,h)
    int nb = nh >> 4, h = nh & 15;
    long tok0 = (long)nb * 2048;
    long qrow0 = qp * 256;

    int rg = lane >> 3, cg = (lane & 7) ^ rg;

    // stage both Q tiles FIRST (oldest vmcnt entries; wave-private rows)
    const f16* qsrc0 = Qp + (tok0 + qrow0) * 1024 + h * 64;
    const f16* qsrc1 = qsrc0 + 128 * 1024;
#pragma unroll
    for (int t = 0; t < 4; ++t) {
        int rb = w * 32 + t * 8;
        gload16(qsrc0 + (rb + rg) * 1024 + cg * 8, &Ps0[rb * 64]);
        gload16(qsrc1 + (rb + rg) * 1024 + cg * 8, &Ps1[rb * 64]);
    }
    // K/V tiles 0 and 1
    const f16* kptr = Kp + (tok0 + w * 16 + rg) * 1024 + h * 64 + cg * 8;
    const f16* vptr = Vt + ((long)h * 64 + w * 16 + rg) * 8192 + tok0 + cg * 8;
    gload16(kptr, &Ks[0][(w * 16) * 64]);
    gload16(kptr + 8 * 1024, &Ks[0][(w * 16 + 8) * 64]);
    gload16(vptr, &Vs[0][(w * 16) * 64]);
    gload16(vptr + (long)8 * 8192, &Vs[0][(w * 16 + 8) * 64]);
    gload16(kptr + 65536, &Ks[1][(w * 16) * 64]);
    gload16(kptr + 65536 + 8 * 1024, &Ks[1][(w * 16 + 8) * 64]);
    gload16(vptr + 64, &Vs[1][(w * 16) * 64]);
    gload16(vptr + 64 + (long)8 * 8192, &Vs[1][(w * 16 + 8) * 64]);
    const f16* kn = kptr + 2 * 65536;
    const f16* vn = vptr + 2 * 64;

    // hoist Q fragments: own-wave Q loads are the 8 oldest -> vmcnt(8);
    // rows are wave-private so no barrier needed before the reads
    asm volatile("s_waitcnt vmcnt(8)" ::: "memory");
    f16x8 qf0[2][2], qf1[2][2];
#pragma unroll
    for (int ks = 0; ks < 2; ++ks) {
        int cc = (ks * 4 + quad) ^ (l15 & 7);
#pragma unroll
        for (int j = 0; j < 2; ++j) {
            qf0[ks][j] = *(const f16x8*)&Ps0[(w * 32 + j * 16 + l15) * 64 + cc * 8];
            qf1[ks][j] = *(const f16x8*)&Ps1[(w * 32 + j * 16 + l15) * 64 + cc * 8];
        }
    }
    // K/V tile0 complete (cross-wave), tile1 left in flight
    asm volatile("s_waitcnt vmcnt(4)" ::: "memory");
    __builtin_amdgcn_s_barrier();
    __builtin_amdgcn_sched_barrier(0);

    f32x4 oacc0[2][4] = {}, oacc1[2][4] = {};
    float rs0[2] = {0.f, 0.f}, rs1[2] = {0.f, 0.f};
    const f32x4 z4 = {0.f, 0.f, 0.f, 0.f};

    int cur = 0;
    for (int kt = 0; kt < 32; ++kt) {
        // S tiles: K fragments read ONCE, feed both q-tiles
        f32x4 sacc0[4][2], sacc1[4][2];
        __builtin_amdgcn_s_setprio(1);
#pragma unroll
        for (int ks = 0; ks < 2; ++ks) {
            int cc = (ks * 4 + quad) ^ (l15 & 7);
            f16x8 a[4];
#pragma unroll
            for (int t = 0; t < 4; ++t)
                a[t] = *(const f16x8*)&Ks[cur][(t * 16 + l15) * 64 + cc * 8];
#pragma unroll
            for (int i = 0; i < 4; ++i)
#pragma unroll
                for (int j = 0; j < 2; ++j) {
                    if (ks == 0) {
                        sacc0[i][j] = mfma16(a[i], qf0[0][j], z4);
                        sacc1[i][j] = mfma16(a[i], qf1[0][j], z4);
                    } else {
                        sacc0[i][j] = mfma16(a[i], qf0[1][j], sacc0[i][j]);
                        sacc1[i][j] = mfma16(a[i], qf1[1][j], sacc1[i][j]);
                    }
                }
        }
        __builtin_amdgcn_s_setprio(0);
        // async prefetch tile kt+2 into slot (cur+2)%3 (read-fenced last iter)
        if (kt < 30) {
            int nxt = (cur == 0) ? 2 : cur - 1;
            f16* kd = &Ks[nxt][(w * 16) * 64];
            f16* vd = &Vs[nxt][(w * 16) * 64];
            gload16(kn, kd);
            gload16(kn + 8 * 1024, kd + 8 * 64);
            gload16(vn, vd);
            gload16(vn + (long)8 * 8192, vd + 8 * 64);
            kn += 65536;
            vn += 64;
        }
        // exp + rowsum + pack for both tiles (wave-private rows)
#pragma unroll
        for (int i = 0; i < 4; ++i) {
#pragma unroll
            for (int j = 0; j < 2; ++j) {
                int qrow = w * 32 + j * 16 + l15;
                int kl = i * 16 + quad * 4;
                int c = kl >> 3;
                int off = qrow * 64 + ((c ^ (qrow & 7)) << 3) + (kl & 7);
                {
                    float p0 = __builtin_amdgcn_exp2f(sacc0[i][j][0]);
                    float p1 = __builtin_amdgcn_exp2f(sacc0[i][j][1]);
                    float p2 = __builtin_amdgcn_exp2f(sacc0[i][j][2]);
                    float p3 = __builtin_amdgcn_exp2f(sacc0[i][j][3]);
                    rs0[j] += (p0 + p1) + (p2 + p3);
                    f16x2 lo = __builtin_bit_cast(f16x2, __builtin_amdgcn_cvt_pkrtz(p0, p1));
                    f16x2 hi = __builtin_bit_cast(f16x2, __builtin_amdgcn_cvt_pkrtz(p2, p3));
                    f16x4 ph;
                    ph[0] = lo[0]; ph[1] = lo[1]; ph[2] = hi[0]; ph[3] = hi[1];
                    *(f16x4*)&Ps0[off] = ph;
                }
                {
                    float p0 = __builtin_amdgcn_exp2f(sacc1[i][j][0]);
                    float p1 = __builtin_amdgcn_exp2f(sacc1[i][j][1]);
                    float p2 = __builtin_amdgcn_exp2f(sacc1[i][j][2]);
                    float p3 = __builtin_amdgcn_exp2f(sacc1[i][j][3]);
                    rs1[j] += (p0 + p1) + (p2 + p3);
                    f16x2 lo = __builtin_bit_cast(f16x2, __builtin_amdgcn_cvt_pkrtz(p0, p1));
                    f16x2 hi = __builtin_bit_cast(f16x2, __builtin_amdgcn_cvt_pkrtz(p2, p3));
                    f16x4 ph;
                    ph[0] = lo[0]; ph[1] = lo[1]; ph[2] = hi[0]; ph[3] = hi[1];
                    *(f16x4*)&Ps1[off] = ph;
                }
            }
        }
        // PV: V fragments read ONCE, feed both q-tiles
        __builtin_amdgcn_s_setprio(1);
#pragma unroll
        for (int ks = 0; ks < 2; ++ks) {
            int cc = (ks * 4 + quad) ^ (l15 & 7);
            f16x8 bf[4];
#pragma unroll
            for (int j = 0; j < 4; ++j)
                bf[j] = *(const f16x8*)&Vs[cur][(j * 16 + l15) * 64 + cc * 8];
            f16x8 af0[2], af1[2];
#pragma unroll
            for (int i = 0; i < 2; ++i) {
                af0[i] = *(const f16x8*)&Ps0[(w * 32 + i * 16 + l15) * 64 + cc * 8];
                af1[i] = *(const f16x8*)&Ps1[(w * 32 + i * 16 + l15) * 64 + cc * 8];
            }
#pragma unroll
            for (int i = 0; i < 2; ++i)
#pragma unroll
                for (int j = 0; j < 4; ++j) {
                    oacc0[i][j] = mfma16(af0[i], bf[j], oacc0[i][j]);
                    oacc1[i][j] = mfma16(af1[i], bf[j], oacc1[i][j]);
                }
        }
        __builtin_amdgcn_s_setprio(0);
        // counted-vmcnt barrier: tile kt+1 retired, tile kt+2 stays in flight
        if (kt < 31) {
            if (kt < 30)
                asm volatile("s_waitcnt vmcnt(4)" ::: "memory");
            else
                asm volatile("s_waitcnt vmcnt(0)" ::: "memory");
            __builtin_amdgcn_s_barrier();
            __builtin_amdgcn_sched_barrier(0);
        }
        cur = (cur == 2) ? 0 : cur + 1;
    }

    // rowsum reduction across quads; lsi aliases Ks[0] (last read kt=30,
    // fenced by that barrier; writes/reads are wave-private rows)
    float* lsi = (float*)&Ks[0][0];  // 256 floats
#pragma unroll
    for (int j = 0; j < 2; ++j) {
        rs0[j] += __shfl_xor(rs0[j], 16, 64);
        rs0[j] += __shfl_xor(rs0[j], 32, 64);
        rs1[j] += __shfl_xor(rs1[j], 16, 64);
        rs1[j] += __shfl_xor(rs1[j], 32, 64);
    }
    if (lane < 16) {
        lsi[w * 32 + lane] = 1.0f / rs0[0];
        lsi[w * 32 + 16 + lane] = 1.0f / rs0[1];
        lsi[128 + w * 32 + lane] = 1.0f / rs1[0];
        lsi[128 + w * 32 + 16 + lane] = 1.0f / rs1[1];
    }

    long otok = tok0 + qrow0;
#pragma unroll
    for (int i = 0; i < 2; ++i) {
        int qrow = w * 32 + i * 16 + quad * 4;
#pragma unroll
        for (int j = 0; j < 4; ++j) {
            int d = j * 16 + l15;
#pragma unroll
            for (int r = 0; r < 4; ++r) {
                Op[(otok + qrow + r) * 1024 + h * 64 + d] =
                    (f16)(oacc0[i][j][r] * lsi[qrow + r]);
                Op[(otok + 128 + qrow + r) * 1024 + h * 64 + d] =
                    (f16)(oacc1[i][j][r] * lsi[128 + qrow + r]);
            }
        }
    }
}

extern "C" void kernel_launch(void* const* d_in, const int* in_sizes, int n_in,
                              void* d_out, int out_size, void* d_ws, size_t ws_size,
                              hipStream_t stream) {
    const float* q  = (const float*)d_in[0];
    const float* k  = (const float*)d_in[1];
    const float* v  = (const float*)d_in[2];
    // d_in[3] padding_mask, d_in[4] sequence_mask: no effect in reference
    const float* Wq = (const float*)d_in[5];
    const float* bq = (const float*)d_in[6];
    const float* Wk = (const float*)d_in[7];
    const float* bk = (const float*)d_in[8];
    const float* Wv = (const float*)d_in[9];
    const float* bv = (const float*)d_in[10];
    const float* Wo = (const float*)d_in[11];
    const float* bo = (const float*)d_in[12];

    // 64 MB workspace (fp32->f16 conversion fused into the GEMMs):
    //   Qp [ 0, 16MB)   Kp [16, 32MB)   Vt [32, 48MB)   Op [48, 64MB)
    char* ws = (char*)d_ws;
    f16* Qp = (f16*)ws;
    f16* Kp = (f16*)(ws + (16L << 20));
    f16* Vt = (f16*)(ws + (32L << 20));
    f16* Op = (f16*)(ws + (48L << 20));

    qkv_proj<<<dim3(64, 8, 3), 256, 0, stream>>>(q, k, v, Wq, Wk, Wv,
                                                 bq, bk, bv, Qp, Kp, Vt);

    attn256<<<512, 256, 0, stream>>>(Qp, Kp, Vt, Op);

    o_proj<<<dim3(64, 8), 256, 0, stream>>>(Op, Wo, bo, (float*)d_out);
}